// Round 1
// baseline (629.447 us; speedup 1.0000x reference)
//
#include <hip/hip_runtime.h>
#include <math.h>

using short8 = __attribute__((ext_vector_type(8))) short;
using f32x4  = __attribute__((ext_vector_type(4))) float;

// round-to-nearest-even f32 -> bf16 bit pattern
__device__ __forceinline__ short f2bf(float f) {
  union { float f; unsigned u; } cv; cv.f = f;
  unsigned u = cv.u;
  unsigned r = u + 0x7fffu + ((u >> 16) & 1u);
  return (short)(r >> 16);
}

__device__ __forceinline__ float gelu_f(float x) {
  return 0.5f * x * (1.0f + erff(x * 0.7071067811865475f));
}

// ---- kernel 0: pack W rows [q(64) k(64) v(64) mi(64)] x 1024 into bf16; concat biases
__global__ void k_prep(const float* __restrict__ qw, const float* __restrict__ kw,
                       const float* __restrict__ vw, const float* __restrict__ miw,
                       const float* __restrict__ qb, const float* __restrict__ kb,
                       const float* __restrict__ vb, const float* __restrict__ mib,
                       short* __restrict__ Wb, float* __restrict__ biasc) {
  int t = blockIdx.x * 256 + threadIdx.x;   // 0..65535
  int e = t * 4;                            // element in 0..262143
  int which = e >> 16;                      // 65536 elems per matrix
  int off = e & 65535;
  const float* src = which == 0 ? qw : which == 1 ? kw : which == 2 ? vw : miw;
  float4 f = *reinterpret_cast<const float4*>(src + off);
  short s4[4] = { f2bf(f.x), f2bf(f.y), f2bf(f.z), f2bf(f.w) };
  *reinterpret_cast<unsigned long long*>(Wb + e) =
      *reinterpret_cast<unsigned long long*>(s4);
  if (blockIdx.x == 0) {
    int w = threadIdx.x >> 6, h = threadIdx.x & 63;
    const float* bsrc = w == 0 ? qb : w == 1 ? kb : w == 2 ? vb : mib;
    biasc[threadIdx.x] = bsrc[h];
  }
}

// ---- kernel 1: per (b,snt): gather 16 rows, pool, qkv+mi projections via MFMA
__global__ __launch_bounds__(256) void k_main(
    const float* __restrict__ token, const int* __restrict__ kwidx,
    const short* __restrict__ Wb, const float* __restrict__ biasc,
    float* __restrict__ qkv, float* __restrict__ svec) {
  constexpr int AS = 1032;          // LDS row stride in shorts (pad 8 -> 4-bank shift/row)
  __shared__ short A[18 * AS];      // rows 0..15: gathered tile; 16: pooled max; 17: pooled avg
  const int bs = blockIdx.x;
  const int b = bs >> 1, snt = bs & 1;
  const int t = threadIdx.x;
  const int col = t * 4;
  const int* idxp = kwidx + (b * 2 + (1 - snt)) * 8;   // reversed sentence index

  float mx[4], sm[4];
  #pragma unroll 4
  for (int i = 0; i < 16; ++i) {
    const int l = i >> 3, j = i & 7;
    const int sidx = idxp[j];
    const float4 f = *reinterpret_cast<const float4*>(
        token + (size_t)((bs * 2 + l) * 256 + sidx) * 1024 + col);
    float fv[4] = { f.x, f.y, f.z, f.w };
    short s4[4];
    #pragma unroll
    for (int c = 0; c < 4; ++c) {
      if (i == 0) { mx[c] = fv[c]; sm[c] = fv[c]; }
      else { mx[c] = fmaxf(mx[c], fv[c]); sm[c] += fv[c]; }
      s4[c] = f2bf(fv[c]);
    }
    *reinterpret_cast<unsigned long long*>(&A[i * AS + col]) =
        *reinterpret_cast<unsigned long long*>(s4);
  }
  {
    short pm4[4], pa4[4];
    #pragma unroll
    for (int c = 0; c < 4; ++c) { pm4[c] = f2bf(mx[c]); pa4[c] = f2bf(sm[c] * 0.0625f); }
    *reinterpret_cast<unsigned long long*>(&A[16 * AS + col]) =
        *reinterpret_cast<unsigned long long*>(pm4);
    *reinterpret_cast<unsigned long long*>(&A[17 * AS + col]) =
        *reinterpret_cast<unsigned long long*>(pa4);
  }
  __syncthreads();

  // wave w handles col-tiles 4w..4w+3 (W rows 64w..64w+63). wave 3 = mi-proj of pooled rows.
  const int wave = t >> 6, lane = t & 63;
  const int quad = lane >> 4, mrow = lane & 15;
  const short* Abase = (wave == 3) ? &A[(16 + (mrow & 1)) * AS] : &A[mrow * AS];
  const short* w0 = Wb + (size_t)(wave * 64 + mrow) * 1024;

  f32x4 acc[4];
  #pragma unroll
  for (int i = 0; i < 4; ++i)
    #pragma unroll
    for (int r = 0; r < 4; ++r) acc[i][r] = 0.f;

  #pragma unroll 4
  for (int ko = 0; ko < 1024; ko += 32) {
    const int k0 = ko + quad * 8;
    short8 af = *reinterpret_cast<const short8*>(Abase + k0);
    short8 b0 = *reinterpret_cast<const short8*>(w0 + k0);
    short8 b1 = *reinterpret_cast<const short8*>(w0 + 16 * 1024 + k0);
    short8 b2 = *reinterpret_cast<const short8*>(w0 + 32 * 1024 + k0);
    short8 b3 = *reinterpret_cast<const short8*>(w0 + 48 * 1024 + k0);
    acc[0] = __builtin_amdgcn_mfma_f32_16x16x32_bf16(af, b0, acc[0], 0, 0, 0);
    acc[1] = __builtin_amdgcn_mfma_f32_16x16x32_bf16(af, b1, acc[1], 0, 0, 0);
    acc[2] = __builtin_amdgcn_mfma_f32_16x16x32_bf16(af, b2, acc[2], 0, 0, 0);
    acc[3] = __builtin_amdgcn_mfma_f32_16x16x32_bf16(af, b3, acc[3], 0, 0, 0);
  }

  // C/D layout: col = lane&15 (W-row within tile), row = quad*4 + reg (gathered row n)
  const int row0 = quad * 4;
  #pragma unroll
  for (int i = 0; i < 4; ++i) {
    const int T = wave * 4 + i;
    const int hg = T * 16 + mrow;           // global W row 0..255
    const float bias = biasc[hg];
    if (T < 12) {
      const int mat = hg >> 6, h = hg & 63; // 0=q 1=k 2=v
      float* dst = qkv + ((size_t)(bs * 3 + mat) << 10) + h;
      #pragma unroll
      for (int r = 0; r < 4; ++r) dst[(row0 + r) * 64] = acc[i][r] + bias;
    } else {
      const int h = hg - 192;               // mi output
      #pragma unroll
      for (int r = 0; r < 4; ++r) {
        const int n = row0 + r;             // 0 = max-pool proj, 1 = avg-pool proj
        if (n < 2) svec[(bs * 2 + n) * 64 + h] = acc[i][r] + bias;
      }
    }
  }
}

// ---- kernel 2: per b: attention + features + cos + fc0/fc1 + softmax (all f32)
__global__ __launch_bounds__(256) void k_tail(
    const float* __restrict__ qkv, const float* __restrict__ svec,
    const float* __restrict__ interw, const float* __restrict__ interb,
    const float* __restrict__ fc0w, const float* __restrict__ fc0b,
    const float* __restrict__ fc1w, const float* __restrict__ fc1b,
    float* __restrict__ out) {
  const int b = blockIdx.x, t = threadIdx.x;
  __shared__ float qk[96 * 65];     // rows: (s*3+mat)*16+n, padded stride 65
  __shared__ float attL[256];
  __shared__ float eL[2][1024];
  __shared__ float feat[516];
  __shared__ float yv[256];
  __shared__ float hmid[64];
  __shared__ float red[256];

  const float* src = qkv + (size_t)b * 6144;
  for (int i = t; i < 6144; i += 256) {
    int row = i >> 6, h = i & 63;
    qk[row * 65 + h] = src[i];
  }
  feat[260 + t] = svec[b * 256 + t];   // s1_max | s1_avg | s2_max | s2_avg
  __syncthreads();

  // att1 = q[s0] k[s1]^T / 8
  {
    const int n = t >> 4, m = t & 15;
    const float* qrow = &qk[n * 65];            // s0 q
    const float* krow = &qk[(64 + m) * 65];     // s1 k
    float acc = 0.f;
    for (int h = 0; h < 64; ++h) acc += qrow[h] * krow[h];
    attL[n * 16 + m] = acc * 0.125f;
  }
  __syncthreads();
  // e1 = att1 @ v[s1]
  {
    const int h = t & 63, ng = t >> 6;
    for (int rep = 0; rep < 4; ++rep) {
      const int n = rep * 4 + ng;
      float acc = 0.f;
      #pragma unroll
      for (int m = 0; m < 16; ++m) acc += attL[n * 16 + m] * qk[(80 + m) * 65 + h];
      eL[0][n * 64 + h] = acc;
    }
  }
  __syncthreads();
  // att2 = q[s1] k[s0]^T / 8
  {
    const int n = t >> 4, m = t & 15;
    const float* qrow = &qk[(48 + n) * 65];     // s1 q
    const float* krow = &qk[(16 + m) * 65];     // s0 k
    float acc = 0.f;
    for (int h = 0; h < 64; ++h) acc += qrow[h] * krow[h];
    attL[n * 16 + m] = acc * 0.125f;
  }
  __syncthreads();
  // e2 = att2 @ v[s0]
  {
    const int h = t & 63, ng = t >> 6;
    for (int rep = 0; rep < 4; ++rep) {
      const int n = rep * 4 + ng;
      float acc = 0.f;
      #pragma unroll
      for (int m = 0; m < 16; ++m) acc += attL[n * 16 + m] * qk[(32 + m) * 65 + h];
      eL[1][n * 64 + h] = acc;
    }
  }
  __syncthreads();
  // att_feat: [e1max e1mean e2max e2mean]
  {
    const int stat = t >> 6, h = t & 63;
    const float* ee = eL[stat >> 1];
    float r;
    if ((stat & 1) == 0) {
      r = -INFINITY;
      for (int n = 0; n < 16; ++n) r = fmaxf(r, ee[n * 64 + h]);
    } else {
      r = 0.f;
      for (int n = 0; n < 16; ++n) r += ee[n * 64 + h];
      r *= (1.f / 16.f);
    }
    feat[stat * 64 + h] = r;
  }
  __syncthreads();
  // inter projections: i0,i1 <- s1_max ; i2,i3 <- s1_avg
  {
    const int i = t >> 6, h = t & 63;
    const float* x = (i < 2) ? &feat[260] : &feat[324];
    const float* wrow = interw + (i * 64 + h) * 64;
    float acc = interb[i * 64 + h];
    for (int hp = 0; hp < 64; ++hp) acc += x[hp] * wrow[hp];
    yv[i * 64 + h] = acc;
  }
  __syncthreads();
  // cosines: (y0,s2max) (y1,s2avg) (y2,s2max) (y3,s2avg)
  if (t < 4) {
    const float* y = &yv[t * 64];
    const float* z = (t & 1) ? &feat[452] : &feat[388];
    float dy = 0.f, ny = 0.f, nz = 0.f;
    for (int h = 0; h < 64; ++h) { dy += y[h] * z[h]; ny += y[h] * y[h]; nz += z[h] * z[h]; }
    float na = fmaxf(sqrtf(ny), 1e-8f), nb = fmaxf(sqrtf(nz), 1e-8f);
    feat[256 + t] = dy / (na * nb);
  }
  __syncthreads();
  // fc0: 4 partial f-chunks of 129 per output
  {
    const int o = t & 63, part = t >> 6;
    const int f0 = part * 129;
    const float* wrow = fc0w + o * 516;
    float acc = 0.f;
    for (int f = f0; f < f0 + 129; ++f) acc += feat[f] * wrow[f];
    red[t] = acc;
  }
  __syncthreads();
  if (t < 64) {
    float acc = fc0b[t] + red[t] + red[64 + t] + red[128 + t] + red[192 + t];
    hmid[t] = gelu_f(acc);
  }
  __syncthreads();
  if (t == 0) {
    float lg[2];
    for (int c = 0; c < 2; ++c) {
      float acc = fc1b[c];
      for (int o = 0; o < 64; ++o) acc += hmid[o] * fc1w[c * 64 + o];
      lg[c] = gelu_f(acc);
    }
    const float mxv = fmaxf(lg[0], lg[1]);
    const float e0 = expf(lg[0] - mxv), e1v = expf(lg[1] - mxv);
    out[b * 2]     = e0 / (e0 + e1v);
    out[b * 2 + 1] = e1v / (e0 + e1v);
  }
}

extern "C" void kernel_launch(void* const* d_in, const int* in_sizes, int n_in,
                              void* d_out, int out_size, void* d_ws, size_t ws_size,
                              hipStream_t stream) {
  (void)in_sizes; (void)n_in; (void)out_size; (void)ws_size;
  const float* token  = (const float*)d_in[0];
  const int*   kwidx  = (const int*)d_in[1];
  const float* qw     = (const float*)d_in[2];
  const float* qb     = (const float*)d_in[3];
  const float* kw     = (const float*)d_in[4];
  const float* kb     = (const float*)d_in[5];
  const float* vw     = (const float*)d_in[6];
  const float* vb     = (const float*)d_in[7];
  const float* miw    = (const float*)d_in[8];
  const float* mib    = (const float*)d_in[9];
  const float* interw = (const float*)d_in[10];
  const float* interb = (const float*)d_in[11];
  const float* fc0w   = (const float*)d_in[12];
  const float* fc0b   = (const float*)d_in[13];
  const float* fc1w   = (const float*)d_in[14];
  const float* fc1b   = (const float*)d_in[15];
  float* out = (float*)d_out;

  char* ws = (char*)d_ws;
  short* Wb    = (short*)(ws);                 // 256*1024 bf16        = 524288 B
  float* biasc = (float*)(ws + 524288);        // 256 f32              = 1024 B
  float* qkv   = (float*)(ws + 525312);        // 256*3*16*64 f32      = 3145728 B
  float* svec  = (float*)(ws + 3671040);       // 256*2*64 f32         = 131072 B

  k_prep<<<256, 256, 0, stream>>>(qw, kw, vw, miw, qb, kb, vb, mib, Wb, biasc);
  k_main<<<256, 256, 0, stream>>>(token, kwidx, Wb, biasc, qkv, svec);
  k_tail<<<128, 256, 0, stream>>>(qkv, svec, interw, interb, fc0w, fc0b, fc1w, fc1b, out);
}